// Round 1
// baseline (713.028 us; speedup 1.0000x reference)
//
#include <hip/hip_runtime.h>
#include <hip/hip_bf16.h>
#include <stdint.h>

// ---------------------------------------------------------------------------
// AdaptiveAngleConv: 5 angles of (bilinear deform-sample -> 3x3 conv)
// x: (2,256,64,64) f32, weight: (256,256,3,3) f32
// out: 5 x (2,256,190,190) f32 concatenated
// Strategy: xo materialized bf16 NHWC, conv = implicit GEMM w/ mfma 16x16x32
// ---------------------------------------------------------------------------

#define S2F 1.41421356237309515f

__constant__ float c_ox[5][9] = {
  {0.f,0.f,0.f,0.f,0.f,0.f,0.f,0.f,0.f},
  {1.f-S2F, 1.f-S2F*0.5f, 1.f, -S2F*0.5f, 0.f, S2F*0.5f, -1.f, S2F*0.5f-1.f, S2F-1.f},
  {0.f,1.f,2.f,-1.f,0.f,1.f,-2.f,-1.f,0.f},
  {1.f, 1.f+S2F*0.5f, 1.f+S2F, -S2F*0.5f, 0.f, S2F*0.5f, -1.f-S2F, -1.f-S2F*0.5f, -1.f},
  {2.f,2.f,2.f,0.f,0.f,0.f,-2.f,-2.f,-2.f}
};
__constant__ float c_oy[5][9] = {
  {0.f,0.f,0.f,0.f,0.f,0.f,0.f,0.f,0.f},
  {1.f, S2F*0.5f, S2F-1.f, 1.f-S2F*0.5f, 0.f, S2F*0.5f-1.f, 1.f-S2F, -S2F*0.5f, -1.f},
  {2.f,1.f,0.f,1.f,0.f,-1.f,0.f,-1.f,-2.f},
  {1.f+S2F, S2F*0.5f, -1.f, 1.f+S2F*0.5f, 0.f, -1.f-S2F*0.5f, 1.f, -S2F*0.5f, 1.f+S2F},
  {2.f,0.f,-2.f,2.f,0.f,-2.f,2.f,0.f,-2.f}
};

typedef __bf16 bf16x8_t __attribute__((ext_vector_type(8)));
typedef float f32x4_t __attribute__((ext_vector_type(4)));

typedef const __attribute__((address_space(1))) void* as1cp;
typedef __attribute__((address_space(3))) void* as3p;

__device__ __forceinline__ void gload16(const void* g, void* l) {
  __builtin_amdgcn_global_load_lds((as1cp)g, (as3p)l, 16, 0, 0);
}

// x NCHW (2,256,64,64) -> xT NHWC (2,64,64,256) f32
__global__ void k_transpose(const float* __restrict__ x, float* __restrict__ xT) {
  const int v = blockIdx.x, u = blockIdx.y, b = blockIdx.z;
  const int ic = threadIdx.x;
  xT[(((b*64 + u)*64 + v)*256) + ic] =
      x[(((b*256 + ic)*64 + u)*64) + v];
}

// weight OIHW (256,256,3,3) f32 -> wb (9,256,256)=[t][oc][ic] bf16
__global__ void k_wconv(const float* __restrict__ w, __hip_bfloat16* __restrict__ wb) {
  const int tid = blockIdx.x*256 + threadIdx.x;   // < 9*256*256
  const int t = tid >> 16;
  const int rem = tid & 65535;
  const int oc = rem >> 8;
  const int ic = rem & 255;
  wb[tid] = __float2bfloat16(w[(oc*256 + ic)*9 + t]);
}

// bilinear deform-sample -> xo bf16 NHWC (2,192,192,256)
__global__ void k_sample(const float* __restrict__ xT,
                         __hip_bfloat16* __restrict__ xo, int aidx)
{
  const int j = blockIdx.x, i = blockIdx.y;
  const int ic = threadIdx.x;
  const int a = i / 3, r = i - 3*a;
  const int bc = j / 3, s = j - 3*bc;
  const int n = r*3 + s;
  // reference: px = (h_idx+1) + (r-1) + ox = a + r + ox (padded coords, ph=pw=66)
  const float px = (float)(a + r) + c_ox[aidx][n];
  const float py = (float)(bc + s) + c_oy[aidx][n];
  const float fx = floorf(px), fy = floorf(py);
  const float pxc = fminf(fmaxf(px, 0.f), 65.f);
  const float pyc = fminf(fmaxf(py, 0.f), 65.f);
  const int qlx = (int)fminf(fmaxf(fx,      0.f), 65.f);
  const int qrx = (int)fminf(fmaxf(fx + 1.f, 0.f), 65.f);
  const int qly = (int)fminf(fmaxf(fy,      0.f), 65.f);
  const int qry = (int)fminf(fmaxf(fy + 1.f, 0.f), 65.f);
  const float wlx = 1.f + (float)qlx - pxc;
  const float wrx = 1.f - (float)qrx + pxc;
  const float wly = 1.f + (float)qly - pyc;
  const float wry = 1.f - (float)qry + pyc;
  const float glt = wlx*wly, grb = wrx*wry, glb = wlx*wry, grt = wrx*wly;

  const bool inxl = (qlx >= 1) && (qlx <= 64);
  const bool inxr = (qrx >= 1) && (qrx <= 64);
  const bool inyl = (qly >= 1) && (qly <= 64);
  const bool inyr = (qry >= 1) && (qry <= 64);

  #pragma unroll
  for (int b = 0; b < 2; ++b) {
    const float* xb = xT + (size_t)b * (64*64*256);
    float vlt = (inxl && inyl) ? xb[((qlx-1)*64 + (qly-1))*256 + ic] : 0.f;
    float vrb = (inxr && inyr) ? xb[((qrx-1)*64 + (qry-1))*256 + ic] : 0.f;
    float vlb = (inxl && inyr) ? xb[((qlx-1)*64 + (qry-1))*256 + ic] : 0.f;
    float vrt = (inxr && inyl) ? xb[((qrx-1)*64 + (qly-1))*256 + ic] : 0.f;
    float val = glt*vlt + grb*vrb + glb*vlb + grt*vrt;
    xo[(((size_t)b*192 + i)*192 + j)*256 + ic] = __float2bfloat16(val);
  }
}

// implicit-GEMM conv: M=128 px (2 rows x 64 cols), N=128 oc, K=9 taps x 256 ic
// grid (6, 95, 2): x = ntile(2) x coltile(3), y = row-pair, z = batch
__global__ __launch_bounds__(256, 2) void k_conv(
    const __hip_bfloat16* __restrict__ xo,   // [2][192][192][256] bf16
    const __hip_bfloat16* __restrict__ wb,   // [9][256][256] bf16 (t,oc,ic)
    float* __restrict__ out)                 // [2][256][190][190] f32 (this angle)
{
  __shared__ __align__(16) char smem[66048];
  const int tid = threadIdx.x;
  const int nt = blockIdx.x & 1;
  const int ct = blockIdx.x >> 1;
  const int i0 = blockIdx.y * 2;
  const int b  = blockIdx.z;
  const int oc0 = nt * 128;
  const int j0 = ct * 64;

  const int q8   = tid >> 3;           // 0..31
  const int slot = tid & 7;
  const int wv   = tid >> 6;           // wave 0..3
  const int sw   = slot ^ (q8 & 7);    // XOR-swizzled 16B slot (pre-swizzle source)

  const char* xob = (const char*)xo + (size_t)b * (size_t)(192*192*256*2);
  const char* wbc = (const char*)wb;

  int arow[4], acol[4], brow[4];
  #pragma unroll
  for (int p = 0; p < 4; ++p) {
    const int m = p*32 + q8;
    arow[p] = i0 + (m >> 6);
    acol[p] = j0 + (m & 63);
    brow[p] = oc0 + m;
  }

  f32x4_t acc[4][4];
  #pragma unroll
  for (int fm = 0; fm < 4; ++fm)
    #pragma unroll
    for (int fn = 0; fn < 4; ++fn)
      acc[fm][fn] = (f32x4_t){0.f, 0.f, 0.f, 0.f};

  const int lane = tid & 63;
  const int lrow = lane & 15;
  const int lk   = lane >> 4;
  const int wm   = wv >> 1;
  const int wn   = wv & 1;

  auto stage = [&](int kk, int cur) {
    const int t = kk >> 2, icg = kk & 3;
    const int ki = t / 3, kj = t - 3*ki;
    char* sa = smem + cur*16384 + wv*1024;
    char* sb = smem + 32768 + cur*16384 + wv*1024;
    #pragma unroll
    for (int p = 0; p < 4; ++p) {
      int col = acol[p] + kj; col = (col > 191) ? 191 : col;   // garbage cols clamped (never stored)
      const char* ga = xob + (((arow[p] + ki)*192 + col)*256 + icg*64)*2 + sw*16;
      gload16(ga, sa + p*4096);
      const char* gb = wbc + ((t*256 + brow[p])*256 + icg*64)*2 + sw*16;
      gload16(gb, sb + p*4096);
    }
  };

  auto compute = [&](int cur) {
    const char* sa = smem + cur*16384;
    const char* sb = smem + 32768 + cur*16384;
    bf16x8_t af[4][2], bfr[4][2];
    #pragma unroll
    for (int f = 0; f < 4; ++f) {
      const int m = wm*64 + f*16 + lrow;
      const int n = wn*64 + f*16 + lrow;
      #pragma unroll
      for (int ks = 0; ks < 2; ++ks) {
        af[f][ks]  = *(const bf16x8_t*)(sa + m*128 + (((ks*4 + lk) ^ (m & 7)) * 16));
        bfr[f][ks] = *(const bf16x8_t*)(sb + n*128 + (((ks*4 + lk) ^ (n & 7)) * 16));
      }
    }
    #pragma unroll
    for (int fm = 0; fm < 4; ++fm)
      #pragma unroll
      for (int fn = 0; fn < 4; ++fn)
        #pragma unroll
        for (int ks = 0; ks < 2; ++ks)
          acc[fm][fn] = __builtin_amdgcn_mfma_f32_16x16x32_bf16(
              af[fm][ks], bfr[fn][ks], acc[fm][fn], 0, 0, 0);
  };

  stage(0, 0);
  __syncthreads();
  for (int kk = 0; kk < 36; ++kk) {
    const int cur = kk & 1;
    if (kk < 35) stage(kk + 1, cur ^ 1);
    compute(cur);
    __syncthreads();
  }

  // epilogue: LDS transpose to [oc'][m'] (pad 129) for coalesced NCHW stores
  float* eps = (float*)smem;
  #pragma unroll
  for (int fm = 0; fm < 4; ++fm)
    #pragma unroll
    for (int fn = 0; fn < 4; ++fn)
      #pragma unroll
      for (int r = 0; r < 4; ++r)
        eps[(wn*64 + fn*16 + lrow)*129 + (wm*64 + fm*16 + lk*4 + r)] = acc[fm][fn][r];
  __syncthreads();

  float* outb = out + (size_t)b * (size_t)(256*190*190);
  #pragma unroll
  for (int pass = 0; pass < 16; ++pass) {
    const int ocw = pass*8 + (tid >> 5);
    const int m4  = (tid & 31) * 4;
    const int di  = m4 >> 6, jc = m4 & 63;
    const int i = i0 + di, j = j0 + jc;
    const float v0 = eps[ocw*129 + m4 + 0];
    const float v1 = eps[ocw*129 + m4 + 1];
    const float v2 = eps[ocw*129 + m4 + 2];
    const float v3 = eps[ocw*129 + m4 + 3];
    float* dst = outb + ((size_t)(oc0 + ocw)*190 + i)*190 + j;
    if (j + 3 < 190) {
      *(float2*)dst       = make_float2(v0, v1);   // 8B-aligned always
      *(float2*)(dst + 2) = make_float2(v2, v3);
    } else {
      if (j     < 190) dst[0] = v0;
      if (j + 1 < 190) dst[1] = v1;
      if (j + 2 < 190) dst[2] = v2;
      if (j + 3 < 190) dst[3] = v3;
    }
  }
}

extern "C" void kernel_launch(void* const* d_in, const int* in_sizes, int n_in,
                              void* d_out, int out_size, void* d_ws, size_t ws_size,
                              hipStream_t stream)
{
  const float* x = (const float*)d_in[0];
  const float* w = (const float*)d_in[1];
  float* out = (float*)d_out;

  char* ws = (char*)d_ws;
  float*          xT = (float*)ws;                         // 2*64*64*256*4   = 8,388,608 B
  __hip_bfloat16* wb = (__hip_bfloat16*)(ws + 8388608);    // 9*256*256*2     = 1,179,648 B
  __hip_bfloat16* xo = (__hip_bfloat16*)(ws + 9568256);    // 2*192*192*256*2 = 37,748,736 B
  // total ws needed: 47,316,992 B

  k_transpose<<<dim3(64, 64, 2), 256, 0, stream>>>(x, xT);
  k_wconv<<<2304, 256, 0, stream>>>(w, wb);

  for (int aidx = 0; aidx < 5; ++aidx) {
    k_sample<<<dim3(192, 192), 256, 0, stream>>>(xT, xo, aidx);
    k_conv<<<dim3(6, 95, 2), 256, 0, stream>>>(xo, wb, out + (size_t)aidx * 18483200);
  }
}